// Round 12
// baseline (1843.921 us; speedup 1.0000x reference)
//
#include <hip/hip_runtime.h>
#include <hip/hip_bf16.h>
#include <math.h>

#define N_NODES 16000
#define N_EDGES 128000
#define N_GRAPH 64
#define NL 5
#define EPSV 1e-5f
#define SCALE 0.07216878364870323f   // 1/sqrt(192)

// Packed P row per node (ushort), 2048 = 4KB:
//   [0,1024):   Pd granules [hd][ch][{q,vd0,vd1,vd2}]   (dst-only, dwordx2)
//   [1024,2048): Ps granules [hd][ch][{k,vs0,vs1,vs2}]  (src full-use dwordx2; dst reads k)
#define PCK 2048
#define ECOLS 1024   // Wep cols: [0,256)=Eh | [256,1024)=EhT (bupd folded into bias)
#define TILE 16      // edges per block in edge_fused
#define SWZ(r) (((r) & 7) << 2)   // scr col-swizzle (4-ushort granules): 32KB LDS

typedef __hip_bfloat16 bf16;
typedef __attribute__((ext_vector_type(8))) short short8;
typedef __attribute__((ext_vector_type(4))) short s4v;
typedef __attribute__((ext_vector_type(4))) float f32x4;
union S8U { short8 v; s4v h[2]; };

__device__ __forceinline__ ushort f2b(float x) {
    union { float f; uint u; } v; v.f = x;
    uint r = v.u + 0x7fffu + ((v.u >> 16) & 1u);   // RNE
    return (ushort)(r >> 16);
}
__device__ __forceinline__ float b2fu(ushort u) { union { uint u; float f; } v; v.u = (uint)u << 16; return v.f; }
__device__ __forceinline__ float b2f_lo32(uint u) { union { uint u; float f; } v; v.u = u << 16; return v.f; }
__device__ __forceinline__ float b2f_hi32(uint u) { union { uint u; float f; } v; v.u = u & 0xffff0000u; return v.f; }

// ---------------- weight packing (hi/lo bf16, MFMA B-fragment order) ----------------
// frag offset for W[64,M]: t=col/16, s=k/32, lane=(col&15)|(((k&31)>>3)<<4), j=k&7
__global__ void pack_w(const float* __restrict__ Wq, const float* __restrict__ Wk,
                       const float* __restrict__ Wv, const float* __restrict__ Wupd,
                       const float* __restrict__ Wedge,
                       short* __restrict__ Wnp, short* __restrict__ Wep) {
    int idx = blockIdx.x * 256 + threadIdx.x;
    int total = NL * 64 * (PCK + ECOLS);
    if (idx >= total) return;
    int c = idx % (PCK + ECOLS);
    int k = (idx / (PCK + ECOLS)) % 64;
    int l = idx / (64 * (PCK + ECOLS));
    if (c < PCK) {
        int blk = c >> 10, hd = (c >> 8) & 3, ch = (c >> 2) & 63, j = c & 3;
        float v;
        if (blk == 0) {   // Pd: {q, vd0, vd1, vd2}
            if (j == 0) v = Wq[(l*64 + k)*256 + hd*64 + ch];
            else {
                int p = (j - 1)*64 + ch;
                float s = 0.f;
                for (int q = 0; q < 64; ++q)
                    s += Wv[(l*64 + k)*256 + hd*64 + q] * Wupd[(l*192 + q)*192 + p];
                v = s;
            }
        } else {          // Ps: {k, vs0, vs1, vs2}
            if (j == 0) v = Wk[(l*64 + k)*256 + hd*64 + ch];
            else {
                int p = (j - 1)*64 + ch;
                float s = 0.f;
                for (int q = 0; q < 64; ++q)
                    s += Wv[(l*64 + k)*256 + hd*64 + q] * Wupd[(l*192 + 64 + q)*192 + p];
                v = s;
            }
        }
        int t = c >> 4, s = k >> 5, lane = (c & 15) | (((k & 31) >> 3) << 4), jj = k & 7;
        size_t fo = ((size_t)(t*2 + s)*64 + lane)*8 + jj;
        ushort hi = f2b(v);
        ushort lo = f2b(v - b2fu(hi));
        Wnp[(size_t)l*2*64*PCK + fo] = (short)hi;
        Wnp[(size_t)l*2*64*PCK + (size_t)64*PCK + fo] = (short)lo;
    } else {
        int ce = c - PCK;
        float v;
        if (ce < 256) v = Wedge[(l*64 + k)*256 + ce];
        else {
            int cc = ce - 256, hd = cc / 192, p = cc % 192;
            float s = 0.f;
            for (int q = 0; q < 64; ++q)
                s += Wedge[(l*64 + k)*256 + hd*64 + q] * Wupd[(l*192 + 128 + q)*192 + p];
            v = s;
        }
        int t = ce >> 4, s = k >> 5, lane = (ce & 15) | (((k & 31) >> 3) << 4), jj = k & 7;
        size_t fo = ((size_t)(t*2 + s)*64 + lane)*8 + jj;
        ushort hi = f2b(v);
        ushort lo = f2b(v - b2fu(hi));
        Wep[(size_t)l*2*64*ECOLS + fo] = (short)hi;
        Wep[(size_t)l*2*64*ECOLS + (size_t)64*ECOLS + fo] = (short)lo;
    }
}

// Wmsg [192,64] per layer -> hi/lo bf16 B-fragments: tile index (t*6+s), 24 tiles/plane
__global__ void pack_wmsg(const float* __restrict__ Wmsg, short* __restrict__ Wmf) {
    int idx = blockIdx.x * 256 + threadIdx.x;
    if (idx >= NL*192*64) return;
    int col = idx & 63, k = (idx >> 6) % 192, l = idx / (192*64);
    float v = Wmsg[(size_t)(l*192 + k)*64 + col];
    int t = col >> 4, s = k >> 5, lane = (col & 15) | (((k & 31) >> 3) << 4), j = k & 7;
    size_t fo = ((size_t)((t*6 + s)*64) + lane)*8 + j;
    ushort hi = f2b(v);
    ushort lo = f2b(v - b2fu(hi));
    Wmf[(size_t)l*2*12288 + fo] = (short)hi;
    Wmf[(size_t)l*2*12288 + 12288 + fo] = (short)lo;
}

__global__ void pack_b(const float* __restrict__ bq, const float* __restrict__ bk,
                       const float* __restrict__ bv, const float* __restrict__ Wupd,
                       const float* __restrict__ bupd, const float* __restrict__ bedge,
                       float* __restrict__ bnp, float* __restrict__ bep) {
    int idx = blockIdx.x * 256 + threadIdx.x;
    int total = NL * (PCK + ECOLS);
    if (idx >= total) return;
    int c = idx % (PCK + ECOLS);
    int l = idx / (PCK + ECOLS);
    if (c < PCK) {
        int blk = c >> 10, hd = (c >> 8) & 3, ch = (c >> 2) & 63, j = c & 3;
        float v;
        if (blk == 0) {
            if (j == 0) v = bq[l*256 + hd*64 + ch];
            else {
                int p = (j - 1)*64 + ch;
                float s = 0.f;
                for (int k = 0; k < 64; ++k) s += bv[l*256 + hd*64 + k] * Wupd[(l*192 + k)*192 + p];
                v = s;
            }
        } else {
            if (j == 0) v = bk[l*256 + hd*64 + ch];
            else {
                int p = (j - 1)*64 + ch;
                float s = 0.f;
                for (int k = 0; k < 64; ++k) s += bv[l*256 + hd*64 + k] * Wupd[(l*192 + 64 + k)*192 + p];
                v = s;
            }
        }
        bnp[l*PCK + c] = v;
    } else {
        int ce = c - PCK;
        float v;
        if (ce < 256) v = bedge[l*256 + ce];
        else {
            int cc = ce - 256, hd = cc / 192, p = cc % 192;
            float s = bupd[l*192 + p];  // fold bupd here
            for (int k = 0; k < 64; ++k) s += bedge[l*256 + hd*64 + k] * Wupd[(l*192 + 128 + k)*192 + p];
            v = s;
        }
        bep[l*ECOLS + ce] = v;
    }
}

// ---------------- edge sort by dst (counting sort) ----------------
__global__ void hist_k(const int* __restrict__ ei, int* __restrict__ hist) {
    int e = blockIdx.x * 256 + threadIdx.x;
    if (e < N_EDGES) atomicAdd(&hist[ei[N_EDGES + e]], 1);
}

__global__ void scan_k(const int* __restrict__ hist, int* __restrict__ binCur) {
    __shared__ int sBuf[256];
    __shared__ int sCarry;
    int tid = threadIdx.x;
    if (tid == 0) sCarry = 0;
    __syncthreads();
    for (int base = 0; base < N_NODES; base += 256) {
        int v = (base + tid < N_NODES) ? hist[base + tid] : 0;
        sBuf[tid] = v; __syncthreads();
        #pragma unroll
        for (int ofs = 1; ofs < 256; ofs <<= 1) {
            int t = (tid >= ofs) ? sBuf[tid - ofs] : 0;
            __syncthreads();
            sBuf[tid] += t;
            __syncthreads();
        }
        if (base + tid < N_NODES) binCur[base + tid] = sCarry + sBuf[tid] - v;
        __syncthreads();
        if (tid == 0) sCarry += sBuf[255];
        __syncthreads();
    }
}

__global__ void scatter_k(const int* __restrict__ ei, int* __restrict__ binCur,
                          int* __restrict__ perm, int* __restrict__ srcs, int* __restrict__ dsts) {
    int e = blockIdx.x * 256 + threadIdx.x;
    if (e < N_EDGES) {
        int d = ei[N_EDGES + e];
        int pos = atomicAdd(&binCur[d], 1);
        perm[pos] = e;
        srcs[pos] = ei[e];
        dsts[pos] = d;
    }
}

// ---------------- initial embeddings ----------------
__global__ void init_h(const float* __restrict__ x, const float* __restrict__ W_atom,
                       const float* __restrict__ b_atom, float* __restrict__ h) {
    int idx = blockIdx.x * 256 + threadIdx.x;   // N*64
    int d = idx & 63, n = idx >> 6;
    float s = b_atom[d];
    #pragma unroll
    for (int j = 0; j < 4; ++j) s += x[n*4 + j] * W_atom[j*64 + d];
    h[idx] = s;
}

__global__ void init_e(const float* __restrict__ ea, const float* __restrict__ We1,
                       const float* __restrict__ be1, const float* __restrict__ We2,
                       const float* __restrict__ be2, float* __restrict__ ef) {
    __shared__ float sT[4][64];
    int tid = threadIdx.x, d = tid & 63, sub = tid >> 6;
    int e = blockIdx.x * 4 + sub;
    float s = be1[d];
    #pragma unroll
    for (int j = 0; j < 9; ++j) s += ea[e*9 + j] * We1[j*64 + d];
    float x64 = s * 64.f;
    float sp = (x64 > 64.f) ? s : log1pf(__expf(fminf(x64, 64.f))) * (1.f/64.f);
    sT[sub][d] = sp;   // wave-local
    float acc = be2[d];
    #pragma unroll
    for (int k = 0; k < 64; ++k) acc += sT[sub][k] * We2[k*64 + d];
    ef[(size_t)e*64 + d] = acc;
}

// ---------------- ef A-fragments (hi/lo), once per run: efA[tile][pl][s][lane][8] ----------------
__global__ void ef_frag(const float* __restrict__ ef, const int* __restrict__ perm,
                        ushort* __restrict__ efA) {
    int b = blockIdx.x, lane = threadIdx.x;   // 64 threads
    int ep = perm[b*16 + (lane & 15)];
    const float* ar = ef + (size_t)ep*64 + ((lane >> 4) << 3);
    ushort* out = efA + (size_t)b*2048;
    #pragma unroll
    for (int s = 0; s < 2; ++s) {
        #pragma unroll
        for (int j = 0; j < 8; ++j) {
            float v = ar[s*32 + j];
            ushort hi = f2b(v);
            ushort lo = f2b(v - b2fu(hi));
            out[s*512 + lane*8 + j] = hi;
            out[1024 + s*512 + lane*8 + j] = lo;
        }
    }
}

// ---------------- MFMA projection (hi/lo split): out_bf16[rows,M] = A_f32[rows,64]@W + b ----------
#define CPAD 260
__global__ __launch_bounds__(256, 8) void proj_mfma(
    const float* __restrict__ A, const short* __restrict__ Whi, const short* __restrict__ Wlo,
    const float* __restrict__ bias, ushort* __restrict__ out, int M) {
    __shared__ short aHi[2*64*8];
    __shared__ short aLo[2*64*8];
    __shared__ ushort cTile[16*CPAD];
    int tid = threadIdx.x;
    int row0 = blockIdx.y * 16;
    int col0 = blockIdx.x * 256;
    {
        int r = tid >> 4, k0 = (tid & 15) * 4;
        const float4 v = *(const float4*)(A + (size_t)(row0 + r)*64 + k0);
        int s = k0 >> 5, lane = r | (((k0 & 31) >> 3) << 4), j0 = k0 & 7;
        ushort4 hb, lb;
        hb.x = f2b(v.x); lb.x = f2b(v.x - b2fu(hb.x));
        hb.y = f2b(v.y); lb.y = f2b(v.y - b2fu(hb.y));
        hb.z = f2b(v.z); lb.z = f2b(v.z - b2fu(hb.z));
        hb.w = f2b(v.w); lb.w = f2b(v.w - b2fu(hb.w));
        *(ushort4*)&aHi[(s*64 + lane)*8 + j0] = hb;
        *(ushort4*)&aLo[(s*64 + lane)*8 + j0] = lb;
    }
    __syncthreads();
    int w = tid >> 6, lane = tid & 63;
    short8 a0h = *(const short8*)&aHi[(0*64 + lane)*8];
    short8 a1h = *(const short8*)&aHi[(1*64 + lane)*8];
    short8 a0l = *(const short8*)&aLo[(0*64 + lane)*8];
    short8 a1l = *(const short8*)&aLo[(1*64 + lane)*8];
    int cl = lane & 15, rg = lane >> 4;
    #pragma unroll
    for (int nt = 0; nt < 4; ++nt) {
        int t = (col0 >> 4) + w*4 + nt;
        const short* bph = Whi + ((size_t)(t*2)*64 + lane)*8;
        const short* bpl = Wlo + ((size_t)(t*2)*64 + lane)*8;
        short8 b0h = *(const short8*)bph;
        short8 b1h = *(const short8*)(bph + 64*8);
        short8 b0l = *(const short8*)bpl;
        short8 b1l = *(const short8*)(bpl + 64*8);
        f32x4 acc = {0.f, 0.f, 0.f, 0.f};
        acc = __builtin_amdgcn_mfma_f32_16x16x32_bf16(a0h, b0h, acc, 0, 0, 0);
        acc = __builtin_amdgcn_mfma_f32_16x16x32_bf16(a1h, b1h, acc, 0, 0, 0);
        acc = __builtin_amdgcn_mfma_f32_16x16x32_bf16(a0l, b0h, acc, 0, 0, 0);
        acc = __builtin_amdgcn_mfma_f32_16x16x32_bf16(a1l, b1h, acc, 0, 0, 0);
        acc = __builtin_amdgcn_mfma_f32_16x16x32_bf16(a0h, b0l, acc, 0, 0, 0);
        acc = __builtin_amdgcn_mfma_f32_16x16x32_bf16(a1h, b1l, acc, 0, 0, 0);
        int ccol = w*64 + nt*16 + cl;
        float bv = bias[col0 + ccol];
        #pragma unroll
        for (int r = 0; r < 4; ++r)
            cTile[(rg*4 + r)*CPAD + ccol] = f2b(acc[r] + bv);
    }
    __syncthreads();
    {
        int r = tid >> 4, cs = (tid & 15) * 16;
        ushort* dst = out + (size_t)(row0 + r)*M + col0 + cs;
        const ushort* srcp = &cTile[r*CPAD + cs];
        #pragma unroll
        for (int q = 0; q < 4; ++q)
            *(ushort4*)(dst + q*4) = *(const ushort4*)(srcp + q*4);
    }
}

// ---------------- HF = h @ Wfea + bfea (f32, residual path) ----------------
__global__ __launch_bounds__(256) void hf_proj(const float* __restrict__ h,
                                               const float* __restrict__ Wfea,
                                               const float* __restrict__ bfea,
                                               float* __restrict__ HF) {
    __shared__ float sW[64*64];
    __shared__ __align__(16) float sA[4][64];
    int tid = threadIdx.x;
    for (int i = tid; i < 4096; i += 256) sW[i] = Wfea[i];
    int c = tid & 63, no = tid >> 6;
    int n0 = blockIdx.x * 4;
    sA[no][c] = h[(size_t)(n0 + no)*64 + c];
    __syncthreads();
    float acc = bfea[c];
    #pragma unroll
    for (int k4 = 0; k4 < 16; ++k4) {
        float4 av = *(const float4*)&sA[no][k4*4];
        acc += av.x*sW[(k4*4+0)*64+c] + av.y*sW[(k4*4+1)*64+c]
             + av.z*sW[(k4*4+2)*64+c] + av.w*sW[(k4*4+3)*64+c];
    }
    HF[(size_t)(n0 + no)*64 + c] = acc;
}

// ---------------- fused per-edge (dst-sorted): barrier-free 4-wave, swizzled 32KB scr ---------
// 256 thr = 4 waves; wave hd owns head hd for TILE=16 edges. dst is wave-uniform ->
// dst-side granules (D,Kd) cached in registers across the sorted run (scalar branch).
__global__ __launch_bounds__(256, 5) void edge_fused(
    const ushort* __restrict__ Pu, const ushort* __restrict__ efA,
    const short* __restrict__ Wef, const float* __restrict__ bef,
    const int* __restrict__ srcs, const int* __restrict__ dsts,
    const short* __restrict__ Wmf, const float* __restrict__ bmsg,
    const float* __restrict__ g_ln, const float* __restrict__ be_ln,
    const float* __restrict__ g_msg, const float* __restrict__ be_msg,
    float* __restrict__ agg) {
    __shared__ __align__(16) ushort scr[4][TILE][256];  // 32 KB, col ^ SWZ(row) swizzle
    int tid = threadIdx.x, lane = tid & 63, hd = tid >> 6;
    int e0 = blockIdx.x * TILE;
    int cl = lane & 15, rg = lane >> 4;
    // ---- phase 0: EP tiles for this head (A from precomputed efA fragments) ----
    {
        const ushort* fa = efA + (size_t)blockIdx.x * 2048;
        short8 a0h = *(const short8*)(fa + lane*8);
        short8 a1h = *(const short8*)(fa + 512 + lane*8);
        short8 a0l = *(const short8*)(fa + 1024 + lane*8);
        short8 a1l = *(const short8*)(fa + 1536 + lane*8);
        #pragma unroll
        for (int tt = 0; tt < 16; ++tt) {
            int tg = (tt < 4) ? (hd*4 + tt) : (16 + hd*12 + (tt - 4));
            const short* bph = Wef + ((size_t)(tg*2)*64 + lane)*8;
            const short* bpl = bph + (size_t)64*ECOLS;
            short8 b0h = *(const short8*)bph;
            short8 b1h = *(const short8*)(bph + 512);
            short8 b0l = *(const short8*)bpl;
            short8 b1l = *(const short8*)(bpl + 512);
            float bv = bef[tg*16 + cl];
            f32x4 acc = {bv, bv, bv, bv};
            acc = __builtin_amdgcn_mfma_f32_16x16x32_bf16(a0h, b0h, acc, 0, 0, 0);
            acc = __builtin_amdgcn_mfma_f32_16x16x32_bf16(a1h, b1h, acc, 0, 0, 0);
            acc = __builtin_amdgcn_mfma_f32_16x16x32_bf16(a0l, b0h, acc, 0, 0, 0);
            acc = __builtin_amdgcn_mfma_f32_16x16x32_bf16(a1l, b1h, acc, 0, 0, 0);
            acc = __builtin_amdgcn_mfma_f32_16x16x32_bf16(a0h, b0l, acc, 0, 0, 0);
            acc = __builtin_amdgcn_mfma_f32_16x16x32_bf16(a1h, b1l, acc, 0, 0, 0);
            int wcol = (tt < 4) ? (tt*16 + cl) : (64 + (tt - 4)*16 + cl);
            #pragma unroll
            for (int r = 0; r < 4; ++r) {
                int row = rg*4 + r;
                scr[hd][row][wcol ^ SWZ(row)] = f2b(acc[r]);
            }
        }
    }
    // ---- phase 1: gating; dst granules cached across sorted runs (wave-uniform branch) ----
    float gl0 = g_ln[lane], gl1 = g_ln[64 + lane], gl2 = g_ln[128 + lane];
    float bl0 = be_ln[lane], bl1 = be_ln[64 + lane], bl2 = be_ln[128 + lane];
    int prevDst = -1;
    uint2 D = {0, 0}, Kd = {0, 0};
    #pragma unroll 4
    for (int it = 0; it < TILE; ++it) {
        int xw = SWZ(it);
        int src = srcs[e0 + it], dst = dsts[e0 + it];
        if (dst != prevDst) {   // wave-uniform: scalar cmp+branch, skipped ~13/16 times
            D  = *(const uint2*)(Pu + (size_t)dst*PCK + hd*256 + (lane << 2));
            Kd = *(const uint2*)(Pu + (size_t)dst*PCK + 1024 + hd*256 + (lane << 2));
            prevDst = dst;
        }
        const uint2 S = *(const uint2*)(Pu + (size_t)src*PCK + 1024 + hd*256 + (lane << 2));
        float q   = b2f_lo32(D.x),  vd0 = b2f_hi32(D.x);
        float vd1 = b2f_lo32(D.y),  vd2 = b2f_hi32(D.y);
        float kd  = b2f_lo32(Kd.x);
        float ks  = b2f_lo32(S.x),  vs0 = b2f_hi32(S.x);
        float vs1 = b2f_lo32(S.y),  vs2 = b2f_hi32(S.y);
        float eh = b2fu(scr[hd][it][lane ^ xw]);
        float a0 = q*kd*SCALE, a1 = q*ks*SCALE, a2 = q*eh*SCALE;
        float s = a0 + a1 + a2, ss = a0*a0 + a1*a1 + a2*a2;
        #pragma unroll
        for (int m = 1; m < 64; m <<= 1) { s += __shfl_xor(s, m); ss += __shfl_xor(ss, m); }
        float mu = s * (1.f/192.f);
        float var = ss * (1.f/192.f) - mu*mu;
        float rstd = rsqrtf(var + EPSV);
        float g0 = __builtin_amdgcn_rcpf(1.f + __expf(-((a0 - mu)*rstd*gl0 + bl0)));
        float g1 = __builtin_amdgcn_rcpf(1.f + __expf(-((a1 - mu)*rstd*gl1 + bl1)));
        float g2 = __builtin_amdgcn_rcpf(1.f + __expf(-((a2 - mu)*rstd*gl2 + bl2)));
        float vu0 = vd0 + vs0 + b2fu(scr[hd][it][(64 + lane) ^ xw]);
        float vu1 = vd1 + vs1 + b2fu(scr[hd][it][(128 + lane) ^ xw]);
        float vu2 = vd2 + vs2 + b2fu(scr[hd][it][(192 + lane) ^ xw]);
        scr[hd][it][(64 + lane) ^ xw]  = f2b(g0*vu0);
        scr[hd][it][(128 + lane) ^ xw] = f2b(g1*vu1);
        scr[hd][it][(192 + lane) ^ xw] = f2b(g2*vu2);
    }
    // ---- phase 2: msg-GEMM (hi/lo W) + fragment-layout LN + run-merged scatter ----
    float bmsv[4], gmv[4], bmv[4];
    #pragma unroll
    for (int t = 0; t < 4; ++t) {
        bmsv[t] = bmsg[t*16 + cl];
        gmv[t]  = g_msg[t*16 + cl];
        bmv[t]  = be_msg[t*16 + cl];
    }
    int dstr[4];
    #pragma unroll
    for (int r = 0; r < 4; ++r) dstr[r] = dsts[e0 + rg*4 + r];
    f32x4 acc[4];
    #pragma unroll
    for (int t = 0; t < 4; ++t) acc[t] = (f32x4){bmsv[t], bmsv[t], bmsv[t], bmsv[t]};
    #pragma unroll
    for (int s = 0; s < 6; ++s) {
        S8U a;
        int c0 = 64 + s*32 + rg*8, xs = SWZ(cl);
        a.h[0] = *(const s4v*)&scr[hd][cl][c0 ^ xs];
        a.h[1] = *(const s4v*)&scr[hd][cl][(c0 + 4) ^ xs];
        #pragma unroll
        for (int t = 0; t < 4; ++t) {
            const short* bp = &Wmf[((size_t)((t*6 + s)*64) + lane)*8];
            short8 bh = *(const short8*)bp;
            short8 bl = *(const short8*)(bp + 12288);
            acc[t] = __builtin_amdgcn_mfma_f32_16x16x32_bf16(a.v, bh, acc[t], 0, 0, 0);
            acc[t] = __builtin_amdgcn_mfma_f32_16x16x32_bf16(a.v, bl, acc[t], 0, 0, 0);
        }
    }
    float nv[4][4];
    #pragma unroll
    for (int r = 0; r < 4; ++r) {
        float s1 = acc[0][r] + acc[1][r] + acc[2][r] + acc[3][r];
        float s2 = acc[0][r]*acc[0][r] + acc[1][r]*acc[1][r]
                 + acc[2][r]*acc[2][r] + acc[3][r]*acc[3][r];
        #pragma unroll
        for (int m = 1; m < 16; m <<= 1) { s1 += __shfl_xor(s1, m); s2 += __shfl_xor(s2, m); }
        float mu = s1 * (1.f/64.f);
        float var = s2 * (1.f/64.f) - mu*mu;
        float rstd = rsqrtf(var + EPSV);
        #pragma unroll
        for (int t = 0; t < 4; ++t) nv[t][r] = (acc[t][r] - mu)*rstd*gmv[t] + bmv[t];
    }
    // run-merge (dsts sorted -> dstr non-decreasing); one atomic flush per distinct dst
    int cur = dstr[0];
    float r0 = nv[0][0], r1 = nv[1][0], r2 = nv[2][0], r3 = nv[3][0];
    #pragma unroll
    for (int r = 1; r < 4; ++r) {
        if (dstr[r] == cur) {
            r0 += nv[0][r]; r1 += nv[1][r]; r2 += nv[2][r]; r3 += nv[3][r];
        } else {
            float* base = &agg[(size_t)cur*256 + hd*64];
            atomicAdd(base + 0*16 + cl, r0);
            atomicAdd(base + 1*16 + cl, r1);
            atomicAdd(base + 2*16 + cl, r2);
            atomicAdd(base + 3*16 + cl, r3);
            cur = dstr[r];
            r0 = nv[0][r]; r1 = nv[1][r]; r2 = nv[2][r]; r3 = nv[3][r];
        }
    }
    {
        float* base = &agg[(size_t)cur*256 + hd*64];
        atomicAdd(base + 0*16 + cl, r0);
        atomicAdd(base + 1*16 + cl, r1);
        atomicAdd(base + 2*16 + cl, r2);
        atomicAdd(base + 3*16 + cl, r3);
    }
}

// ---------------- out = agg@Wcat + bcat, with BN partial sums ----------------
__global__ __launch_bounds__(256, 2) void agg_out(
    const float* __restrict__ agg, const float* __restrict__ Wcat, const float* __restrict__ bcat,
    float* __restrict__ out, float* __restrict__ bnsum, float* __restrict__ bnss) {
    __shared__ float sW[256 * 64];
    __shared__ __align__(16) float sA[4][256];
    __shared__ float sR[4][64];
    int tid = threadIdx.x;
    for (int i = tid; i < 256*64; i += 256) sW[i] = Wcat[i];
    int c = tid & 63, no = tid >> 6;
    float bc = bcat[c];
    float psum = 0.f, psq = 0.f;
    __syncthreads();
    int nbase = blockIdx.x * 64;
    for (int it = 0; it < 16; ++it) {
        for (int i = tid; i < 1024; i += 256)
            sA[i >> 8][i & 255] = agg[(size_t)(nbase + it*4 + (i >> 8))*256 + (i & 255)];
        __syncthreads();
        float acc = bc;
        #pragma unroll
        for (int k4 = 0; k4 < 64; ++k4) {
            float4 av = *(const float4*)&sA[no][k4*4];
            acc += av.x*sW[(k4*4+0)*64 + c] + av.y*sW[(k4*4+1)*64 + c]
                 + av.z*sW[(k4*4+2)*64 + c] + av.w*sW[(k4*4+3)*64 + c];
        }
        out[(size_t)(nbase + it*4 + no)*64 + c] = acc;
        psum += acc; psq += acc*acc;
        __syncthreads();
    }
    sR[no][c] = psum; __syncthreads();
    if (no == 0) atomicAdd(&bnsum[c], sR[0][c] + sR[1][c] + sR[2][c] + sR[3][c]);
    __syncthreads();
    sR[no][c] = psq; __syncthreads();
    if (no == 0) atomicAdd(&bnss[c], sR[0][c] + sR[1][c] + sR[2][c] + sR[3][c]);
}

// ---------------- BN finalize + silu + residual ----------------
__global__ void bn_silu(const float* __restrict__ out, const float* __restrict__ HF,
                        const float* __restrict__ bnsum, const float* __restrict__ bnss,
                        const float* __restrict__ g_bn, const float* __restrict__ be_bn,
                        float* __restrict__ h) {
    int idx = blockIdx.x * 256 + threadIdx.x;   // N*64
    int c = idx & 63;
    float mu = bnsum[c] * (1.f/N_NODES);
    float var = bnss[c] * (1.f/N_NODES) - mu*mu;
    float rstd = rsqrtf(var + EPSV);
    float v = (out[idx] - mu)*rstd*g_bn[c] + be_bn[c];
    float sv = v / (1.f + __expf(-v));
    h[idx] = sv + HF[idx];
}

// ---------------- fused readout: segment mean (sorted batch) + MLP head ----------------
__device__ __forceinline__ int lbound(const int* __restrict__ a, int n, int v) {
    int lo = 0, hi = n;
    while (lo < hi) { int m = (lo + hi) >> 1; if (a[m] < v) lo = m + 1; else hi = m; }
    return lo;
}

__global__ __launch_bounds__(256) void pool_head(
    const float* __restrict__ h, const int* __restrict__ batch,
    const float* __restrict__ Wfc, const float* __restrict__ bfc,
    const float* __restrict__ Wout, const float* __restrict__ bout,
    float* __restrict__ d_out) {
    __shared__ float sPart[4][64];
    __shared__ float sP[64];
    __shared__ float red[128];
    int g = blockIdx.x, tid = threadIdx.x;
    int lo = lbound(batch, N_NODES, g);
    int hi = lbound(batch, N_NODES, g + 1);
    int c = tid & 63, rg = tid >> 6;
    float s = 0.f;
    for (int n = lo + rg; n < hi; n += 4) s += h[(size_t)n*64 + c];
    sPart[rg][c] = s;
    __syncthreads();
    if (tid < 64)
        sP[tid] = (sPart[0][tid] + sPart[1][tid] + sPart[2][tid] + sPart[3][tid])
                  * (1.f / fmaxf((float)(hi - lo), 1.f));
    __syncthreads();
    if (tid < 128) {
        float acc = bfc[tid];
        #pragma unroll
        for (int k = 0; k < 64; ++k) acc += sP[k] * Wfc[k*128 + tid];
        float z = acc / (1.f + __expf(-acc));
        red[tid] = z * Wout[tid];
    }
    __syncthreads();
    for (int s1 = 64; s1 > 0; s1 >>= 1) {
        if (tid < s1 && tid + s1 < 128) red[tid] += red[tid + s1];
        __syncthreads();
    }
    if (tid == 0) d_out[g] = red[0] + bout[0];
}

// ---------------- launcher ----------------
extern "C" void kernel_launch(void* const* d_in, const int* in_sizes, int n_in,
                              void* d_out, int out_size, void* d_ws, size_t ws_size,
                              hipStream_t stream) {
    const float* x        = (const float*)d_in[0];
    const float* edge_attr= (const float*)d_in[1];
    const int*   ei       = (const int*)  d_in[2];
    const int*   batch    = (const int*)  d_in[3];
    const float* W_atom=(const float*)d_in[4];  const float* b_atom=(const float*)d_in[5];
    const float* We1  =(const float*)d_in[6];   const float* be1  =(const float*)d_in[7];
    const float* We2  =(const float*)d_in[8];   const float* be2  =(const float*)d_in[9];
    const float* Wq   =(const float*)d_in[10];  const float* bq   =(const float*)d_in[11];
    const float* Wk   =(const float*)d_in[12];  const float* bk   =(const float*)d_in[13];
    const float* Wv   =(const float*)d_in[14];  const float* bv   =(const float*)d_in[15];
    const float* Wedge=(const float*)d_in[16];  const float* bedge=(const float*)d_in[17];
    const float* Wfea =(const float*)d_in[18];  const float* bfea =(const float*)d_in[19];
    const float* Wcat =(const float*)d_in[20];  const float* bcat =(const float*)d_in[21];
    const float* Wupd =(const float*)d_in[22];  const float* bupd =(const float*)d_in[23];
    const float* Wmsg =(const float*)d_in[24];  const float* bmsg =(const float*)d_in[25];
    const float* g_msg=(const float*)d_in[26];  const float* be_msg=(const float*)d_in[27];
    const float* g_ln =(const float*)d_in[28];  const float* be_ln=(const float*)d_in[29];
    const float* g_bn =(const float*)d_in[30];  const float* be_bn=(const float*)d_in[31];
    const float* Wfc  =(const float*)d_in[32];  const float* bfc  =(const float*)d_in[33];
    const float* Wout =(const float*)d_in[34];  const float* bout =(const float*)d_in[35];

    char* ws = (char*)d_ws;
    size_t off = 0;
    auto alloc = [&](size_t bytes) {
        void* p = ws + off;
        off += (bytes + 255) & ~(size_t)255;
        return p;
    };
    short* Wnp  = (short*)alloc((size_t)NL*2*64*PCK*2);    // hi+lo planes
    float* bnp  = (float*)alloc((size_t)NL*PCK*4);
    short* Wep  = (short*)alloc((size_t)NL*2*64*ECOLS*2);  // hi+lo planes
    float* bep  = (float*)alloc((size_t)NL*ECOLS*4);
    short* Wmf  = (short*)alloc((size_t)NL*2*12288*2);     // hi+lo planes
    float* h    = (float*)alloc((size_t)N_NODES*64*4);
    float* ef   = (float*)alloc((size_t)N_EDGES*64*4);
    ushort* efA = (ushort*)alloc((size_t)(N_EDGES/TILE)*2048*2);
    ushort* P   = (ushort*)alloc((size_t)N_NODES*PCK*2);
    float* HF   = (float*)alloc((size_t)N_NODES*64*4);
    float* agg  = (float*)alloc((size_t)N_NODES*256*4);
    float* outb = (float*)alloc((size_t)N_NODES*64*4);
    float* bnsum= (float*)alloc(64*4);
    float* bnss = (float*)alloc(64*4);
    int* histB  = (int*)alloc((size_t)N_NODES*4);
    int* binCur = (int*)alloc((size_t)N_NODES*4);
    int* perm   = (int*)alloc((size_t)N_EDGES*4);
    int* srcs   = (int*)alloc((size_t)N_EDGES*4);
    int* dsts   = (int*)alloc((size_t)N_EDGES*4);
    if (off > ws_size) return;  // fail visibly

    {
        int total = NL*64*(PCK+ECOLS);
        pack_w<<<(total+255)/256, 256, 0, stream>>>(Wq, Wk, Wv, Wupd, Wedge, Wnp, Wep);
        int tb = NL*(PCK+ECOLS);
        pack_b<<<(tb+255)/256, 256, 0, stream>>>(bq, bk, bv, Wupd, bupd, bedge, bnp, bep);
        pack_wmsg<<<(NL*192*64+255)/256, 256, 0, stream>>>(Wmsg, Wmf);
    }
    // edge sort by dst
    hipMemsetAsync(histB, 0, (size_t)N_NODES*4, stream);
    hist_k<<<(N_EDGES+255)/256, 256, 0, stream>>>(ei, histB);
    scan_k<<<1, 256, 0, stream>>>(histB, binCur);
    scatter_k<<<(N_EDGES+255)/256, 256, 0, stream>>>(ei, binCur, perm, srcs, dsts);

    init_h<<<(N_NODES*64)/256, 256, 0, stream>>>(x, W_atom, b_atom, h);
    init_e<<<N_EDGES/4, 256, 0, stream>>>(edge_attr, We1, be1, We2, be2, ef);
    ef_frag<<<N_EDGES/TILE, 64, 0, stream>>>(ef, perm, efA);

    for (int l = 0; l < NL; ++l) {
        const short* Wh = Wnp + (size_t)l*2*64*PCK;
        proj_mfma<<<dim3(PCK/256, N_NODES/16), 256, 0, stream>>>(
            h, Wh, Wh + (size_t)64*PCK, bnp + l*PCK, P, PCK);
        hf_proj<<<N_NODES/4, 256, 0, stream>>>(h, Wfea + (size_t)l*64*64, bfea + l*64, HF);
        hipMemsetAsync(agg, 0, (size_t)N_NODES*256*4, stream);
        hipMemsetAsync(bnsum, 0, 64*4, stream);
        hipMemsetAsync(bnss, 0, 64*4, stream);
        edge_fused<<<N_EDGES/TILE, 256, 0, stream>>>(
            P, efA, Wep + (size_t)l*2*64*ECOLS, bep + l*ECOLS, srcs, dsts,
            Wmf + (size_t)l*2*12288, bmsg + l*64,
            g_ln + l*192, be_ln + l*192, g_msg + l*64, be_msg + l*64, agg);
        agg_out<<<N_NODES/64, 256, 0, stream>>>(agg, Wcat + (size_t)l*256*64, bcat + l*64,
                                                outb, bnsum, bnss);
        bn_silu<<<(N_NODES*64)/256, 256, 0, stream>>>(outb, HF, bnsum, bnss,
                                                      g_bn + l*64, be_bn + l*64, h);
    }
    pool_head<<<N_GRAPH, 256, 0, stream>>>(h, batch, Wfc, bfc, Wout, bout, (float*)d_out);
}

// Round 13
// 1698.673 us; speedup vs baseline: 1.0855x; 1.0855x over previous
//
#include <hip/hip_runtime.h>
#include <hip/hip_bf16.h>
#include <math.h>

#define N_NODES 16000
#define N_EDGES 128000
#define N_GRAPH 64
#define NL 5
#define EPSV 1e-5f
#define SCALE 0.07216878364870323f   // 1/sqrt(192)

// Packed P row per node (ushort), 2048 = 4KB:
//   [0,1024):   Pd granules [hd][ch][{q,vd0,vd1,vd2}]   (dst-only, dwordx2)
//   [1024,2048): Ps granules [hd][ch][{k,vs0,vs1,vs2}]  (src full-use dwordx2; dst reads k)
#define PCK 2048
#define ECOLS 1024   // Wep cols: [0,256)=Eh | [256,1024)=EhT (bupd folded into bias)
#define TILE 16      // edges per block in edge_fused
#define SWZ(r) (((r) & 7) << 2)   // scr col-swizzle (4-ushort granules): 32KB LDS

typedef __hip_bfloat16 bf16;
typedef __attribute__((ext_vector_type(8))) short short8;
typedef __attribute__((ext_vector_type(4))) short s4v;
typedef __attribute__((ext_vector_type(4))) float f32x4;
union S8U { short8 v; s4v h[2]; };

__device__ __forceinline__ ushort f2b(float x) {
    union { float f; uint u; } v; v.f = x;
    uint r = v.u + 0x7fffu + ((v.u >> 16) & 1u);   // RNE
    return (ushort)(r >> 16);
}
__device__ __forceinline__ ushort f2b_n(float x) {   // native cast path (compiler picks cvt insts)
    union { bf16 b; ushort u; } v; v.b = __float2bfloat16(x);
    return v.u;
}
__device__ __forceinline__ float b2fu(ushort u) { union { uint u; float f; } v; v.u = (uint)u << 16; return v.f; }
__device__ __forceinline__ float b2f_lo32(uint u) { union { uint u; float f; } v; v.u = u << 16; return v.f; }
__device__ __forceinline__ float b2f_hi32(uint u) { union { uint u; float f; } v; v.u = u & 0xffff0000u; return v.f; }

// ---------------- weight packing (hi/lo bf16, MFMA B-fragment order) ----------------
// frag offset for W[64,M]: t=col/16, s=k/32, lane=(col&15)|(((k&31)>>3)<<4), j=k&7
__global__ void pack_w(const float* __restrict__ Wq, const float* __restrict__ Wk,
                       const float* __restrict__ Wv, const float* __restrict__ Wupd,
                       const float* __restrict__ Wedge,
                       short* __restrict__ Wnp, short* __restrict__ Wep) {
    int idx = blockIdx.x * 256 + threadIdx.x;
    int total = NL * 64 * (PCK + ECOLS);
    if (idx >= total) return;
    int c = idx % (PCK + ECOLS);
    int k = (idx / (PCK + ECOLS)) % 64;
    int l = idx / (64 * (PCK + ECOLS));
    if (c < PCK) {
        int blk = c >> 10, hd = (c >> 8) & 3, ch = (c >> 2) & 63, j = c & 3;
        float v;
        if (blk == 0) {   // Pd: {q, vd0, vd1, vd2}
            if (j == 0) v = Wq[(l*64 + k)*256 + hd*64 + ch];
            else {
                int p = (j - 1)*64 + ch;
                float s = 0.f;
                for (int q = 0; q < 64; ++q)
                    s += Wv[(l*64 + k)*256 + hd*64 + q] * Wupd[(l*192 + q)*192 + p];
                v = s;
            }
        } else {          // Ps: {k, vs0, vs1, vs2}
            if (j == 0) v = Wk[(l*64 + k)*256 + hd*64 + ch];
            else {
                int p = (j - 1)*64 + ch;
                float s = 0.f;
                for (int q = 0; q < 64; ++q)
                    s += Wv[(l*64 + k)*256 + hd*64 + q] * Wupd[(l*192 + 64 + q)*192 + p];
                v = s;
            }
        }
        int t = c >> 4, s = k >> 5, lane = (c & 15) | (((k & 31) >> 3) << 4), jj = k & 7;
        size_t fo = ((size_t)(t*2 + s)*64 + lane)*8 + jj;
        ushort hi = f2b(v);
        ushort lo = f2b(v - b2fu(hi));
        Wnp[(size_t)l*2*64*PCK + fo] = (short)hi;
        Wnp[(size_t)l*2*64*PCK + (size_t)64*PCK + fo] = (short)lo;
    } else {
        int ce = c - PCK;
        float v;
        if (ce < 256) v = Wedge[(l*64 + k)*256 + ce];
        else {
            int cc = ce - 256, hd = cc / 192, p = cc % 192;
            float s = 0.f;
            for (int q = 0; q < 64; ++q)
                s += Wedge[(l*64 + k)*256 + hd*64 + q] * Wupd[(l*192 + 128 + q)*192 + p];
            v = s;
        }
        int t = ce >> 4, s = k >> 5, lane = (ce & 15) | (((k & 31) >> 3) << 4), jj = k & 7;
        size_t fo = ((size_t)(t*2 + s)*64 + lane)*8 + jj;
        ushort hi = f2b(v);
        ushort lo = f2b(v - b2fu(hi));
        Wep[(size_t)l*2*64*ECOLS + fo] = (short)hi;
        Wep[(size_t)l*2*64*ECOLS + (size_t)64*ECOLS + fo] = (short)lo;
    }
}

// Wmsg [192,64] per layer -> hi/lo bf16 B-fragments: tile index (t*6+s), 24 tiles/plane
__global__ void pack_wmsg(const float* __restrict__ Wmsg, short* __restrict__ Wmf) {
    int idx = blockIdx.x * 256 + threadIdx.x;
    if (idx >= NL*192*64) return;
    int col = idx & 63, k = (idx >> 6) % 192, l = idx / (192*64);
    float v = Wmsg[(size_t)(l*192 + k)*64 + col];
    int t = col >> 4, s = k >> 5, lane = (col & 15) | (((k & 31) >> 3) << 4), j = k & 7;
    size_t fo = ((size_t)((t*6 + s)*64) + lane)*8 + j;
    ushort hi = f2b(v);
    ushort lo = f2b(v - b2fu(hi));
    Wmf[(size_t)l*2*12288 + fo] = (short)hi;
    Wmf[(size_t)l*2*12288 + 12288 + fo] = (short)lo;
}

// generic row-weight pack: W[K,64] per layer -> hi/lo B-fragments, tile idx (t*nks+s)
__global__ void pack_rw(const float* __restrict__ W, short* __restrict__ Wf, int K) {
    int idx = blockIdx.x * 256 + threadIdx.x;
    if (idx >= NL*K*64) return;
    int col = idx & 63, k = (idx >> 6) % K, l = idx / (K*64);
    float v = W[(size_t)(l*K + k)*64 + col];
    int t = col >> 4, s = k >> 5, lane = (col & 15) | (((k & 31) >> 3) << 4), j = k & 7;
    int nks = K >> 5;
    size_t plane = (size_t)nks * 2048;
    size_t fo = ((size_t)((t*nks + s)*64) + lane)*8 + j;
    ushort hi = f2b(v);
    ushort lo = f2b(v - b2fu(hi));
    Wf[(size_t)l*2*plane + fo] = (short)hi;
    Wf[(size_t)l*2*plane + plane + fo] = (short)lo;
}

__global__ void pack_b(const float* __restrict__ bq, const float* __restrict__ bk,
                       const float* __restrict__ bv, const float* __restrict__ Wupd,
                       const float* __restrict__ bupd, const float* __restrict__ bedge,
                       float* __restrict__ bnp, float* __restrict__ bep) {
    int idx = blockIdx.x * 256 + threadIdx.x;
    int total = NL * (PCK + ECOLS);
    if (idx >= total) return;
    int c = idx % (PCK + ECOLS);
    int l = idx / (PCK + ECOLS);
    if (c < PCK) {
        int blk = c >> 10, hd = (c >> 8) & 3, ch = (c >> 2) & 63, j = c & 3;
        float v;
        if (blk == 0) {
            if (j == 0) v = bq[l*256 + hd*64 + ch];
            else {
                int p = (j - 1)*64 + ch;
                float s = 0.f;
                for (int k = 0; k < 64; ++k) s += bv[l*256 + hd*64 + k] * Wupd[(l*192 + k)*192 + p];
                v = s;
            }
        } else {
            if (j == 0) v = bk[l*256 + hd*64 + ch];
            else {
                int p = (j - 1)*64 + ch;
                float s = 0.f;
                for (int k = 0; k < 64; ++k) s += bv[l*256 + hd*64 + k] * Wupd[(l*192 + 64 + k)*192 + p];
                v = s;
            }
        }
        bnp[l*PCK + c] = v;
    } else {
        int ce = c - PCK;
        float v;
        if (ce < 256) v = bedge[l*256 + ce];
        else {
            int cc = ce - 256, hd = cc / 192, p = cc % 192;
            float s = bupd[l*192 + p];  // fold bupd here
            for (int k = 0; k < 64; ++k) s += bedge[l*256 + hd*64 + k] * Wupd[(l*192 + 128 + k)*192 + p];
            v = s;
        }
        bep[l*ECOLS + ce] = v;
    }
}

// ---------------- edge sort by dst (counting sort) ----------------
__global__ void hist_k(const int* __restrict__ ei, int* __restrict__ hist) {
    int e = blockIdx.x * 256 + threadIdx.x;
    if (e < N_EDGES) atomicAdd(&hist[ei[N_EDGES + e]], 1);
}

__global__ void scan_k(const int* __restrict__ hist, int* __restrict__ binCur) {
    __shared__ int sBuf[256];
    __shared__ int sCarry;
    int tid = threadIdx.x;
    if (tid == 0) sCarry = 0;
    __syncthreads();
    for (int base = 0; base < N_NODES; base += 256) {
        int v = (base + tid < N_NODES) ? hist[base + tid] : 0;
        sBuf[tid] = v; __syncthreads();
        #pragma unroll
        for (int ofs = 1; ofs < 256; ofs <<= 1) {
            int t = (tid >= ofs) ? sBuf[tid - ofs] : 0;
            __syncthreads();
            sBuf[tid] += t;
            __syncthreads();
        }
        if (base + tid < N_NODES) binCur[base + tid] = sCarry + sBuf[tid] - v;
        __syncthreads();
        if (tid == 0) sCarry += sBuf[255];
        __syncthreads();
    }
}

__global__ void scatter_k(const int* __restrict__ ei, int* __restrict__ binCur,
                          int* __restrict__ perm, int* __restrict__ srcs, int* __restrict__ dsts) {
    int e = blockIdx.x * 256 + threadIdx.x;
    if (e < N_EDGES) {
        int d = ei[N_EDGES + e];
        int pos = atomicAdd(&binCur[d], 1);
        perm[pos] = e;
        srcs[pos] = ei[e];
        dsts[pos] = d;
    }
}

// ---------------- initial embeddings ----------------
__global__ void init_h(const float* __restrict__ x, const float* __restrict__ W_atom,
                       const float* __restrict__ b_atom, float* __restrict__ h) {
    int idx = blockIdx.x * 256 + threadIdx.x;   // N*64
    int d = idx & 63, n = idx >> 6;
    float s = b_atom[d];
    #pragma unroll
    for (int j = 0; j < 4; ++j) s += x[n*4 + j] * W_atom[j*64 + d];
    h[idx] = s;
}

__global__ void init_e(const float* __restrict__ ea, const float* __restrict__ We1,
                       const float* __restrict__ be1, const float* __restrict__ We2,
                       const float* __restrict__ be2, float* __restrict__ ef) {
    __shared__ float sT[4][64];
    int tid = threadIdx.x, d = tid & 63, sub = tid >> 6;
    int e = blockIdx.x * 4 + sub;
    float s = be1[d];
    #pragma unroll
    for (int j = 0; j < 9; ++j) s += ea[e*9 + j] * We1[j*64 + d];
    float x64 = s * 64.f;
    float sp = (x64 > 64.f) ? s : log1pf(__expf(fminf(x64, 64.f))) * (1.f/64.f);
    sT[sub][d] = sp;   // wave-local
    float acc = be2[d];
    #pragma unroll
    for (int k = 0; k < 64; ++k) acc += sT[sub][k] * We2[k*64 + d];
    ef[(size_t)e*64 + d] = acc;
}

// ---------------- ef A-fragments (hi/lo), once per run: efA[tile][pl][s][lane][8] ----------------
__global__ void ef_frag(const float* __restrict__ ef, const int* __restrict__ perm,
                        ushort* __restrict__ efA) {
    int b = blockIdx.x, lane = threadIdx.x;   // 64 threads
    int ep = perm[b*16 + (lane & 15)];
    const float* ar = ef + (size_t)ep*64 + ((lane >> 4) << 3);
    ushort* out = efA + (size_t)b*2048;
    #pragma unroll
    for (int s = 0; s < 2; ++s) {
        #pragma unroll
        for (int j = 0; j < 8; ++j) {
            float v = ar[s*32 + j];
            ushort hi = f2b(v);
            ushort lo = f2b(v - b2fu(hi));
            out[s*512 + lane*8 + j] = hi;
            out[1024 + s*512 + lane*8 + j] = lo;
        }
    }
}

// ---------------- MFMA projection (hi/lo split): out_bf16[rows,M] = A_f32[rows,64]@W + b ----------
#define CPAD 260
__global__ __launch_bounds__(256, 8) void proj_mfma(
    const float* __restrict__ A, const short* __restrict__ Whi, const short* __restrict__ Wlo,
    const float* __restrict__ bias, ushort* __restrict__ out, int M) {
    __shared__ short aHi[2*64*8];
    __shared__ short aLo[2*64*8];
    __shared__ ushort cTile[16*CPAD];
    int tid = threadIdx.x;
    int row0 = blockIdx.y * 16;
    int col0 = blockIdx.x * 256;
    {
        int r = tid >> 4, k0 = (tid & 15) * 4;
        const float4 v = *(const float4*)(A + (size_t)(row0 + r)*64 + k0);
        int s = k0 >> 5, lane = r | (((k0 & 31) >> 3) << 4), j0 = k0 & 7;
        ushort4 hb, lb;
        hb.x = f2b(v.x); lb.x = f2b(v.x - b2fu(hb.x));
        hb.y = f2b(v.y); lb.y = f2b(v.y - b2fu(hb.y));
        hb.z = f2b(v.z); lb.z = f2b(v.z - b2fu(hb.z));
        hb.w = f2b(v.w); lb.w = f2b(v.w - b2fu(hb.w));
        *(ushort4*)&aHi[(s*64 + lane)*8 + j0] = hb;
        *(ushort4*)&aLo[(s*64 + lane)*8 + j0] = lb;
    }
    __syncthreads();
    int w = tid >> 6, lane = tid & 63;
    short8 a0h = *(const short8*)&aHi[(0*64 + lane)*8];
    short8 a1h = *(const short8*)&aHi[(1*64 + lane)*8];
    short8 a0l = *(const short8*)&aLo[(0*64 + lane)*8];
    short8 a1l = *(const short8*)&aLo[(1*64 + lane)*8];
    int cl = lane & 15, rg = lane >> 4;
    #pragma unroll
    for (int nt = 0; nt < 4; ++nt) {
        int t = (col0 >> 4) + w*4 + nt;
        const short* bph = Whi + ((size_t)(t*2)*64 + lane)*8;
        const short* bpl = Wlo + ((size_t)(t*2)*64 + lane)*8;
        short8 b0h = *(const short8*)bph;
        short8 b1h = *(const short8*)(bph + 64*8);
        short8 b0l = *(const short8*)bpl;
        short8 b1l = *(const short8*)(bpl + 64*8);
        f32x4 acc = {0.f, 0.f, 0.f, 0.f};
        acc = __builtin_amdgcn_mfma_f32_16x16x32_bf16(a0h, b0h, acc, 0, 0, 0);
        acc = __builtin_amdgcn_mfma_f32_16x16x32_bf16(a1h, b1h, acc, 0, 0, 0);
        acc = __builtin_amdgcn_mfma_f32_16x16x32_bf16(a0l, b0h, acc, 0, 0, 0);
        acc = __builtin_amdgcn_mfma_f32_16x16x32_bf16(a1l, b1h, acc, 0, 0, 0);
        acc = __builtin_amdgcn_mfma_f32_16x16x32_bf16(a0h, b0l, acc, 0, 0, 0);
        acc = __builtin_amdgcn_mfma_f32_16x16x32_bf16(a1h, b1l, acc, 0, 0, 0);
        int ccol = w*64 + nt*16 + cl;
        float bv = bias[col0 + ccol];
        #pragma unroll
        for (int r = 0; r < 4; ++r)
            cTile[(rg*4 + r)*CPAD + ccol] = f2b(acc[r] + bv);
    }
    __syncthreads();
    {
        int r = tid >> 4, cs = (tid & 15) * 16;
        ushort* dst = out + (size_t)(row0 + r)*M + col0 + cs;
        const ushort* srcp = &cTile[r*CPAD + cs];
        #pragma unroll
        for (int q = 0; q < 4; ++q)
            *(ushort4*)(dst + q*4) = *(const ushort4*)(srcp + q*4);
    }
}

// ---------------- generic MFMA row-GEMM: out_f32[rows,64] = A_f32[rows,K]@W + b (+BN stats) ----
// 16 rows/block, 4 waves (wave = 16-col tile), A hi/lo split at runtime, W hi/lo pre-packed.
__global__ __launch_bounds__(256, 4) void row_mfma(
    const float* __restrict__ A, const short* __restrict__ Wf, const float* __restrict__ bias,
    float* __restrict__ out, int nks, float* __restrict__ bnsum, float* __restrict__ bnss) {
    __shared__ short aHi[8*64*8];
    __shared__ short aLo[8*64*8];
    int tid = threadIdx.x;
    int row0 = blockIdx.x * 16;
    int K = nks << 5;
    int cpt = K >> 4;                 // cols per thread: 16 (K=256) or 4 (K=64)
    {
        int r = tid >> 4, c0 = (tid & 15) * cpt;
        const float* ap = A + (size_t)(row0 + r)*K + c0;
        for (int q = 0; q < cpt; q += 4) {
            float4 v = *(const float4*)(ap + q);
            ushort4 hb, lb;
            hb.x = f2b(v.x); lb.x = f2b(v.x - b2fu(hb.x));
            hb.y = f2b(v.y); lb.y = f2b(v.y - b2fu(hb.y));
            hb.z = f2b(v.z); lb.z = f2b(v.z - b2fu(hb.z));
            hb.w = f2b(v.w); lb.w = f2b(v.w - b2fu(hb.w));
            int k = c0 + q;
            int s = k >> 5, lane = r | (((k & 31) >> 3) << 4), jj = k & 7;
            *(ushort4*)&aHi[(s*64 + lane)*8 + jj] = hb;
            *(ushort4*)&aLo[(s*64 + lane)*8 + jj] = lb;
        }
    }
    __syncthreads();
    int w = tid >> 6, lane = tid & 63;
    int cl = lane & 15, rg = lane >> 4;
    size_t plane = (size_t)nks * 2048;
    f32x4 acc = {0.f, 0.f, 0.f, 0.f};
    for (int s = 0; s < nks; ++s) {
        short8 ah = *(const short8*)&aHi[(s*64 + lane)*8];
        short8 al = *(const short8*)&aLo[(s*64 + lane)*8];
        const short* bp = Wf + ((size_t)((w*nks + s)*64) + lane)*8;
        short8 bh = *(const short8*)bp;
        short8 bl = *(const short8*)(bp + plane);
        acc = __builtin_amdgcn_mfma_f32_16x16x32_bf16(ah, bh, acc, 0, 0, 0);
        acc = __builtin_amdgcn_mfma_f32_16x16x32_bf16(al, bh, acc, 0, 0, 0);
        acc = __builtin_amdgcn_mfma_f32_16x16x32_bf16(ah, bl, acc, 0, 0, 0);
    }
    int col = w*16 + cl;
    float bc = bias[col];
    float psum = 0.f, psq = 0.f;
    #pragma unroll
    for (int r2 = 0; r2 < 4; ++r2) {
        float v = acc[r2] + bc;
        out[(size_t)(row0 + rg*4 + r2)*64 + col] = v;
        psum += v; psq += v*v;
    }
    if (bnsum) {
        psum += __shfl_xor(psum, 16); psum += __shfl_xor(psum, 32);
        psq  += __shfl_xor(psq, 16);  psq  += __shfl_xor(psq, 32);
        if (rg == 0) { atomicAdd(&bnsum[col], psum); atomicAdd(&bnss[col], psq); }
    }
}

// ---------------- fused per-edge (dst-sorted): barrier-free 4-wave, swizzled 32KB scr ---------
__global__ __launch_bounds__(256, 5) void edge_fused(
    const ushort* __restrict__ Pu, const ushort* __restrict__ efA,
    const short* __restrict__ Wef, const float* __restrict__ bef,
    const int* __restrict__ srcs, const int* __restrict__ dsts,
    const short* __restrict__ Wmf, const float* __restrict__ bmsg,
    const float* __restrict__ g_ln, const float* __restrict__ be_ln,
    const float* __restrict__ g_msg, const float* __restrict__ be_msg,
    float* __restrict__ agg) {
    __shared__ __align__(16) ushort scr[4][TILE][256];  // 32 KB, col ^ SWZ(row) swizzle
    int tid = threadIdx.x, lane = tid & 63, hd = tid >> 6;
    int e0 = blockIdx.x * TILE;
    int cl = lane & 15, rg = lane >> 4;
    // ---- phase 0: EP tiles for this head (A from precomputed efA fragments) ----
    {
        const ushort* fa = efA + (size_t)blockIdx.x * 2048;
        short8 a0h = *(const short8*)(fa + lane*8);
        short8 a1h = *(const short8*)(fa + 512 + lane*8);
        short8 a0l = *(const short8*)(fa + 1024 + lane*8);
        short8 a1l = *(const short8*)(fa + 1536 + lane*8);
        #pragma unroll
        for (int tt = 0; tt < 16; ++tt) {
            int tg = (tt < 4) ? (hd*4 + tt) : (16 + hd*12 + (tt - 4));
            const short* bph = Wef + ((size_t)(tg*2)*64 + lane)*8;
            const short* bpl = bph + (size_t)64*ECOLS;
            short8 b0h = *(const short8*)bph;
            short8 b1h = *(const short8*)(bph + 512);
            short8 b0l = *(const short8*)bpl;
            short8 b1l = *(const short8*)(bpl + 512);
            float bv = bef[tg*16 + cl];
            f32x4 acc = {bv, bv, bv, bv};
            acc = __builtin_amdgcn_mfma_f32_16x16x32_bf16(a0h, b0h, acc, 0, 0, 0);
            acc = __builtin_amdgcn_mfma_f32_16x16x32_bf16(a1h, b1h, acc, 0, 0, 0);
            acc = __builtin_amdgcn_mfma_f32_16x16x32_bf16(a0l, b0h, acc, 0, 0, 0);
            acc = __builtin_amdgcn_mfma_f32_16x16x32_bf16(a1l, b1h, acc, 0, 0, 0);
            acc = __builtin_amdgcn_mfma_f32_16x16x32_bf16(a0h, b0l, acc, 0, 0, 0);
            acc = __builtin_amdgcn_mfma_f32_16x16x32_bf16(a1h, b1l, acc, 0, 0, 0);
            int wcol = (tt < 4) ? (tt*16 + cl) : (64 + (tt - 4)*16 + cl);
            #pragma unroll
            for (int r = 0; r < 4; ++r) {
                int row = rg*4 + r;
                scr[hd][row][wcol ^ SWZ(row)] = f2b_n(acc[r]);
            }
        }
    }
    // ---- phase 1: gating; dst granules cached across sorted runs (wave-uniform branch) ----
    float gl0 = g_ln[lane], gl1 = g_ln[64 + lane], gl2 = g_ln[128 + lane];
    float bl0 = be_ln[lane], bl1 = be_ln[64 + lane], bl2 = be_ln[128 + lane];
    int prevDst = -1;
    uint2 D = {0, 0}, Kd = {0, 0};
    #pragma unroll 4
    for (int it = 0; it < TILE; ++it) {
        int xw = SWZ(it);
        int src = srcs[e0 + it], dst = dsts[e0 + it];
        if (dst != prevDst) {   // wave-uniform scalar branch
            D  = *(const uint2*)(Pu + (size_t)dst*PCK + hd*256 + (lane << 2));
            Kd = *(const uint2*)(Pu + (size_t)dst*PCK + 1024 + hd*256 + (lane << 2));
            prevDst = dst;
        }
        const uint2 S = *(const uint2*)(Pu + (size_t)src*PCK + 1024 + hd*256 + (lane << 2));
        float q   = b2f_lo32(D.x),  vd0 = b2f_hi32(D.x);
        float vd1 = b2f_lo32(D.y),  vd2 = b2f_hi32(D.y);
        float kd  = b2f_lo32(Kd.x);
        float ks  = b2f_lo32(S.x),  vs0 = b2f_hi32(S.x);
        float vs1 = b2f_lo32(S.y),  vs2 = b2f_hi32(S.y);
        float eh = b2fu(scr[hd][it][lane ^ xw]);
        float a0 = q*kd*SCALE, a1 = q*ks*SCALE, a2 = q*eh*SCALE;
        float s = a0 + a1 + a2, ss = a0*a0 + a1*a1 + a2*a2;
        #pragma unroll
        for (int m = 1; m < 64; m <<= 1) { s += __shfl_xor(s, m); ss += __shfl_xor(ss, m); }
        float mu = s * (1.f/192.f);
        float var = ss * (1.f/192.f) - mu*mu;
        float rstd = rsqrtf(var + EPSV);
        float g0 = __builtin_amdgcn_rcpf(1.f + __expf(-((a0 - mu)*rstd*gl0 + bl0)));
        float g1 = __builtin_amdgcn_rcpf(1.f + __expf(-((a1 - mu)*rstd*gl1 + bl1)));
        float g2 = __builtin_amdgcn_rcpf(1.f + __expf(-((a2 - mu)*rstd*gl2 + bl2)));
        float vu0 = vd0 + vs0 + b2fu(scr[hd][it][(64 + lane) ^ xw]);
        float vu1 = vd1 + vs1 + b2fu(scr[hd][it][(128 + lane) ^ xw]);
        float vu2 = vd2 + vs2 + b2fu(scr[hd][it][(192 + lane) ^ xw]);
        scr[hd][it][(64 + lane) ^ xw]  = f2b_n(g0*vu0);
        scr[hd][it][(128 + lane) ^ xw] = f2b_n(g1*vu1);
        scr[hd][it][(192 + lane) ^ xw] = f2b_n(g2*vu2);
    }
    // ---- phase 2: msg-GEMM (hi/lo W) + fragment-layout LN + run-merged scatter ----
    float bmsv[4], gmv[4], bmv[4];
    #pragma unroll
    for (int t = 0; t < 4; ++t) {
        bmsv[t] = bmsg[t*16 + cl];
        gmv[t]  = g_msg[t*16 + cl];
        bmv[t]  = be_msg[t*16 + cl];
    }
    int dstr[4];
    #pragma unroll
    for (int r = 0; r < 4; ++r) dstr[r] = dsts[e0 + rg*4 + r];
    f32x4 acc[4];
    #pragma unroll
    for (int t = 0; t < 4; ++t) acc[t] = (f32x4){bmsv[t], bmsv[t], bmsv[t], bmsv[t]};
    #pragma unroll
    for (int s = 0; s < 6; ++s) {
        S8U a;
        int c0 = 64 + s*32 + rg*8, xs = SWZ(cl);
        a.h[0] = *(const s4v*)&scr[hd][cl][c0 ^ xs];
        a.h[1] = *(const s4v*)&scr[hd][cl][(c0 + 4) ^ xs];
        #pragma unroll
        for (int t = 0; t < 4; ++t) {
            const short* bp = &Wmf[((size_t)((t*6 + s)*64) + lane)*8];
            short8 bh = *(const short8*)bp;
            short8 bl = *(const short8*)(bp + 12288);
            acc[t] = __builtin_amdgcn_mfma_f32_16x16x32_bf16(a.v, bh, acc[t], 0, 0, 0);
            acc[t] = __builtin_amdgcn_mfma_f32_16x16x32_bf16(a.v, bl, acc[t], 0, 0, 0);
        }
    }
    float nv[4][4];
    #pragma unroll
    for (int r = 0; r < 4; ++r) {
        float s1 = acc[0][r] + acc[1][r] + acc[2][r] + acc[3][r];
        float s2 = acc[0][r]*acc[0][r] + acc[1][r]*acc[1][r]
                 + acc[2][r]*acc[2][r] + acc[3][r]*acc[3][r];
        #pragma unroll
        for (int m = 1; m < 16; m <<= 1) { s1 += __shfl_xor(s1, m); s2 += __shfl_xor(s2, m); }
        float mu = s1 * (1.f/64.f);
        float var = s2 * (1.f/64.f) - mu*mu;
        float rstd = rsqrtf(var + EPSV);
        #pragma unroll
        for (int t = 0; t < 4; ++t) nv[t][r] = (acc[t][r] - mu)*rstd*gmv[t] + bmv[t];
    }
    // run-merge (dsts sorted -> dstr non-decreasing); one atomic flush per distinct dst
    int cur = dstr[0];
    float r0 = nv[0][0], r1 = nv[1][0], r2 = nv[2][0], r3 = nv[3][0];
    #pragma unroll
    for (int r = 1; r < 4; ++r) {
        if (dstr[r] == cur) {
            r0 += nv[0][r]; r1 += nv[1][r]; r2 += nv[2][r]; r3 += nv[3][r];
        } else {
            float* base = &agg[(size_t)cur*256 + hd*64];
            atomicAdd(base + 0*16 + cl, r0);
            atomicAdd(base + 1*16 + cl, r1);
            atomicAdd(base + 2*16 + cl, r2);
            atomicAdd(base + 3*16 + cl, r3);
            cur = dstr[r];
            r0 = nv[0][r]; r1 = nv[1][r]; r2 = nv[2][r]; r3 = nv[3][r];
        }
    }
    {
        float* base = &agg[(size_t)cur*256 + hd*64];
        atomicAdd(base + 0*16 + cl, r0);
        atomicAdd(base + 1*16 + cl, r1);
        atomicAdd(base + 2*16 + cl, r2);
        atomicAdd(base + 3*16 + cl, r3);
    }
}

// ---------------- BN finalize + silu + residual ----------------
__global__ void bn_silu(const float* __restrict__ out, const float* __restrict__ HF,
                        const float* __restrict__ bnsum, const float* __restrict__ bnss,
                        const float* __restrict__ g_bn, const float* __restrict__ be_bn,
                        float* __restrict__ h) {
    int idx = blockIdx.x * 256 + threadIdx.x;   // N*64
    int c = idx & 63;
    float mu = bnsum[c] * (1.f/N_NODES);
    float var = bnss[c] * (1.f/N_NODES) - mu*mu;
    float rstd = rsqrtf(var + EPSV);
    float v = (out[idx] - mu)*rstd*g_bn[c] + be_bn[c];
    float sv = v / (1.f + __expf(-v));
    h[idx] = sv + HF[idx];
}

// ---------------- fused readout: segment mean (sorted batch) + MLP head ----------------
__device__ __forceinline__ int lbound(const int* __restrict__ a, int n, int v) {
    int lo = 0, hi = n;
    while (lo < hi) { int m = (lo + hi) >> 1; if (a[m] < v) lo = m + 1; else hi = m; }
    return lo;
}

__global__ __launch_bounds__(256) void pool_head(
    const float* __restrict__ h, const int* __restrict__ batch,
    const float* __restrict__ Wfc, const float* __restrict__ bfc,
    const float* __restrict__ Wout, const float* __restrict__ bout,
    float* __restrict__ d_out) {
    __shared__ float sPart[4][64];
    __shared__ float sP[64];
    __shared__ float red[128];
    int g = blockIdx.x, tid = threadIdx.x;
    int lo = lbound(batch, N_NODES, g);
    int hi = lbound(batch, N_NODES, g + 1);
    int c = tid & 63, rg = tid >> 6;
    float s = 0.f;
    for (int n = lo + rg; n < hi; n += 4) s += h[(size_t)n*64 + c];
    sPart[rg][c] = s;
    __syncthreads();
    if (tid < 64)
        sP[tid] = (sPart[0][tid] + sPart[1][tid] + sPart[2][tid] + sPart[3][tid])
                  * (1.f / fmaxf((float)(hi - lo), 1.f));
    __syncthreads();
    if (tid < 128) {
        float acc = bfc[tid];
        #pragma unroll
        for (int k = 0; k < 64; ++k) acc += sP[k] * Wfc[k*128 + tid];
        float z = acc / (1.f + __expf(-acc));
        red[tid] = z * Wout[tid];
    }
    __syncthreads();
    for (int s1 = 64; s1 > 0; s1 >>= 1) {
        if (tid < s1 && tid + s1 < 128) red[tid] += red[tid + s1];
        __syncthreads();
    }
    if (tid == 0) d_out[g] = red[0] + bout[0];
}

// ---------------- launcher ----------------
extern "C" void kernel_launch(void* const* d_in, const int* in_sizes, int n_in,
                              void* d_out, int out_size, void* d_ws, size_t ws_size,
                              hipStream_t stream) {
    const float* x        = (const float*)d_in[0];
    const float* edge_attr= (const float*)d_in[1];
    const int*   ei       = (const int*)  d_in[2];
    const int*   batch    = (const int*)  d_in[3];
    const float* W_atom=(const float*)d_in[4];  const float* b_atom=(const float*)d_in[5];
    const float* We1  =(const float*)d_in[6];   const float* be1  =(const float*)d_in[7];
    const float* We2  =(const float*)d_in[8];   const float* be2  =(const float*)d_in[9];
    const float* Wq   =(const float*)d_in[10];  const float* bq   =(const float*)d_in[11];
    const float* Wk   =(const float*)d_in[12];  const float* bk   =(const float*)d_in[13];
    const float* Wv   =(const float*)d_in[14];  const float* bv   =(const float*)d_in[15];
    const float* Wedge=(const float*)d_in[16];  const float* bedge=(const float*)d_in[17];
    const float* Wfea =(const float*)d_in[18];  const float* bfea =(const float*)d_in[19];
    const float* Wcat =(const float*)d_in[20];  const float* bcat =(const float*)d_in[21];
    const float* Wupd =(const float*)d_in[22];  const float* bupd =(const float*)d_in[23];
    const float* Wmsg =(const float*)d_in[24];  const float* bmsg =(const float*)d_in[25];
    const float* g_msg=(const float*)d_in[26];  const float* be_msg=(const float*)d_in[27];
    const float* g_ln =(const float*)d_in[28];  const float* be_ln=(const float*)d_in[29];
    const float* g_bn =(const float*)d_in[30];  const float* be_bn=(const float*)d_in[31];
    const float* Wfc  =(const float*)d_in[32];  const float* bfc  =(const float*)d_in[33];
    const float* Wout =(const float*)d_in[34];  const float* bout =(const float*)d_in[35];

    char* ws = (char*)d_ws;
    size_t off = 0;
    auto alloc = [&](size_t bytes) {
        void* p = ws + off;
        off += (bytes + 255) & ~(size_t)255;
        return p;
    };
    short* Wnp  = (short*)alloc((size_t)NL*2*64*PCK*2);    // hi+lo planes
    float* bnp  = (float*)alloc((size_t)NL*PCK*4);
    short* Wep  = (short*)alloc((size_t)NL*2*64*ECOLS*2);  // hi+lo planes
    float* bep  = (float*)alloc((size_t)NL*ECOLS*4);
    short* Wmf  = (short*)alloc((size_t)NL*2*12288*2);     // hi+lo planes
    short* Wcf  = (short*)alloc((size_t)NL*2*16384*2);     // Wcat frags (K=256)
    short* Wff  = (short*)alloc((size_t)NL*2*4096*2);      // Wfea frags (K=64)
    float* h    = (float*)alloc((size_t)N_NODES*64*4);
    float* ef   = (float*)alloc((size_t)N_EDGES*64*4);
    ushort* efA = (ushort*)alloc((size_t)(N_EDGES/TILE)*2048*2);
    ushort* P   = (ushort*)alloc((size_t)N_NODES*PCK*2);
    float* HF   = (float*)alloc((size_t)N_NODES*64*4);
    float* agg  = (float*)alloc((size_t)N_NODES*256*4);
    float* outb = (float*)alloc((size_t)N_NODES*64*4);
    float* bnsum= (float*)alloc(64*4);
    float* bnss = (float*)alloc(64*4);
    int* histB  = (int*)alloc((size_t)N_NODES*4);
    int* binCur = (int*)alloc((size_t)N_NODES*4);
    int* perm   = (int*)alloc((size_t)N_EDGES*4);
    int* srcs   = (int*)alloc((size_t)N_EDGES*4);
    int* dsts   = (int*)alloc((size_t)N_EDGES*4);
    if (off > ws_size) return;  // fail visibly

    {
        int total = NL*64*(PCK+ECOLS);
        pack_w<<<(total+255)/256, 256, 0, stream>>>(Wq, Wk, Wv, Wupd, Wedge, Wnp, Wep);
        int tb = NL*(PCK+ECOLS);
        pack_b<<<(tb+255)/256, 256, 0, stream>>>(bq, bk, bv, Wupd, bupd, bedge, bnp, bep);
        pack_wmsg<<<(NL*192*64+255)/256, 256, 0, stream>>>(Wmsg, Wmf);
        pack_rw<<<(NL*256*64+255)/256, 256, 0, stream>>>(Wcat, Wcf, 256);
        pack_rw<<<(NL*64*64+255)/256, 256, 0, stream>>>(Wfea, Wff, 64);
    }
    // edge sort by dst
    hipMemsetAsync(histB, 0, (size_t)N_NODES*4, stream);
    hist_k<<<(N_EDGES+255)/256, 256, 0, stream>>>(ei, histB);
    scan_k<<<1, 256, 0, stream>>>(histB, binCur);
    scatter_k<<<(N_EDGES+255)/256, 256, 0, stream>>>(ei, binCur, perm, srcs, dsts);

    init_h<<<(N_NODES*64)/256, 256, 0, stream>>>(x, W_atom, b_atom, h);
    init_e<<<N_EDGES/4, 256, 0, stream>>>(edge_attr, We1, be1, We2, be2, ef);
    ef_frag<<<N_EDGES/TILE, 64, 0, stream>>>(ef, perm, efA);

    for (int l = 0; l < NL; ++l) {
        const short* Wh = Wnp + (size_t)l*2*64*PCK;
        proj_mfma<<<dim3(PCK/256, N_NODES/16), 256, 0, stream>>>(
            h, Wh, Wh + (size_t)64*PCK, bnp + l*PCK, P, PCK);
        row_mfma<<<N_NODES/16, 256, 0, stream>>>(
            h, Wff + (size_t)l*2*4096, bfea + l*64, HF, 2, nullptr, nullptr);
        hipMemsetAsync(agg, 0, (size_t)N_NODES*256*4, stream);
        hipMemsetAsync(bnsum, 0, 64*4, stream);
        hipMemsetAsync(bnss, 0, 64*4, stream);
        edge_fused<<<N_EDGES/TILE, 256, 0, stream>>>(
            P, efA, Wep + (size_t)l*2*64*ECOLS, bep + l*ECOLS, srcs, dsts,
            Wmf + (size_t)l*2*12288, bmsg + l*64,
            g_ln + l*192, be_ln + l*192, g_msg + l*64, be_msg + l*64, agg);
        row_mfma<<<N_NODES/16, 256, 0, stream>>>(
            agg, Wcf + (size_t)l*2*16384, bcat + l*64, outb, 8, bnsum, bnss);
        bn_silu<<<(N_NODES*64)/256, 256, 0, stream>>>(outb, HF, bnsum, bnss,
                                                      g_bn + l*64, be_bn + l*64, h);
    }
    pool_head<<<N_GRAPH, 256, 0, stream>>>(h, batch, Wfc, bfc, Wout, bout, (float*)d_out);
}